// Round 1
// baseline (1217.275 us; speedup 1.0000x reference)
//
#include <hip/hip_runtime.h>
#include <cstddef>

#define D_MODEL 1024
#define DK 64
#define NH 16
#define NB 2
#define SEQ 2048

// ---------------------------------------------------------------------------
// Kernel 1: fused QKV projection + bias + ReLU.
// grid = (M/64, 48): blockIdx.y -> (proj, head); 64x64 output tile per block.
// ---------------------------------------------------------------------------
__global__ __launch_bounds__(256) void qkv_kernel(
    const float* __restrict__ x,
    const float* __restrict__ Wq, const float* __restrict__ bq,
    const float* __restrict__ Wk, const float* __restrict__ bk,
    const float* __restrict__ Wv, const float* __restrict__ bv,
    float* __restrict__ Qo, float* __restrict__ Ko, float* __restrict__ Vo)
{
    __shared__ float As[64][36];   // pad 36: compute reads are 2-way (free)
    __shared__ float Bs[32][64];

    const int cb   = blockIdx.y;
    const int proj = cb >> 4;
    const int h    = cb & 15;
    const float* W; const float* bias; float* Out;
    if (proj == 0)      { W = Wq; bias = bq; Out = Qo; }
    else if (proj == 1) { W = Wk; bias = bk; Out = Ko; }
    else                { W = Wv; bias = bv; Out = Vo; }
    W    += (size_t)h * (D_MODEL * DK);
    bias += h * DK;

    const int row0 = blockIdx.x * 64;
    const int tid  = threadIdx.x;
    const int ty   = tid >> 4, tx = tid & 15;

    const int arow = tid >> 3;          // 0..31
    const int aseg = (tid & 7) * 4;     // 0..28
    const int wrow = tid >> 3;          // 0..31
    const int wcol = (tid & 7) * 8;     // 0..56

    float acc[4][4] = {};

    for (int k0 = 0; k0 < D_MODEL; k0 += 32) {
        float4 a0 = *(const float4*)&x[(size_t)(row0 + arow)      * D_MODEL + k0 + aseg];
        float4 a1 = *(const float4*)&x[(size_t)(row0 + arow + 32) * D_MODEL + k0 + aseg];
        float4 w0 = *(const float4*)&W[(size_t)(k0 + wrow) * DK + wcol];
        float4 w1 = *(const float4*)&W[(size_t)(k0 + wrow) * DK + wcol + 4];
        *(float4*)&As[arow][aseg]      = a0;   // 36*4=144B rows: 16B-aligned
        *(float4*)&As[arow + 32][aseg] = a1;
        *(float4*)&Bs[wrow][wcol]      = w0;
        *(float4*)&Bs[wrow][wcol + 4]  = w1;
        __syncthreads();
#pragma unroll
        for (int kk = 0; kk < 32; kk++) {
            float a[4], b[4];
#pragma unroll
            for (int i = 0; i < 4; i++) a[i] = As[ty*4+i][kk];
#pragma unroll
            for (int j = 0; j < 4; j++) b[j] = Bs[kk][tx*4+j];
#pragma unroll
            for (int i = 0; i < 4; i++)
#pragma unroll
                for (int j = 0; j < 4; j++)
                    acc[i][j] += a[i] * b[j];
        }
        __syncthreads();
    }

    float bvals[4];
#pragma unroll
    for (int j = 0; j < 4; j++) bvals[j] = bias[tx*4+j];
#pragma unroll
    for (int i = 0; i < 4; i++) {
        const int m  = row0 + ty*4 + i;
        const int b_ = m >> 11;
        const int s_ = m & (SEQ - 1);
        float4 v;
        v.x = fmaxf(acc[i][0] + bvals[0], 0.f);
        v.y = fmaxf(acc[i][1] + bvals[1], 0.f);
        v.z = fmaxf(acc[i][2] + bvals[2], 0.f);
        v.w = fmaxf(acc[i][3] + bvals[3], 0.f);
        *(float4*)&Out[((size_t)(b_*NH + h) * SEQ + s_) * DK + tx*4] = v;
    }
}

// ---------------------------------------------------------------------------
// Kernel 2: flash attention (online softmax), fp32.
// grid = (S/64, B*H); block = 256 threads handles 64 query rows.
// ---------------------------------------------------------------------------
__global__ __launch_bounds__(256) void attn_kernel(
    const float* __restrict__ Q, const float* __restrict__ K,
    const float* __restrict__ V, float* __restrict__ ctx)
{
    __shared__ float Qs[64][65];
    __shared__ float Ks[64][65];
    __shared__ float Vs[64][65];
    __shared__ float Ss[64][65];
    __shared__ float mS[64], lS[64], alphaS[64];
    __shared__ float red[64][4];

    const int bh = blockIdx.y;
    const int qt = blockIdx.x;
    const float* Qp = Q + (size_t)bh * SEQ * DK + (size_t)qt * 64 * DK;
    const float* Kp = K + (size_t)bh * SEQ * DK;
    const float* Vp = V + (size_t)bh * SEQ * DK;

    const int tid = threadIdx.x;
    const int ty  = tid >> 4, tx = tid & 15;
    const int lr  = tid >> 2;           // 0..63 row for staging
    const int lc  = (tid & 3) * 4;      // float4 col base

    // stage Q tile (64x64)
#pragma unroll
    for (int ii = 0; ii < 4; ii++) {
        const int c = lc + ii*16;
        float4 v = *(const float4*)&Qp[lr * DK + c];
        Qs[lr][c+0] = v.x; Qs[lr][c+1] = v.y; Qs[lr][c+2] = v.z; Qs[lr][c+3] = v.w;
    }
    if (tid < 64) { mS[tid] = -1e30f; lS[tid] = 0.f; }

    float o[4][4] = {};
    __syncthreads();

    for (int jt = 0; jt < SEQ/64; jt++) {
        // stage K,V tiles
#pragma unroll
        for (int ii = 0; ii < 4; ii++) {
            const int c = lc + ii*16;
            float4 kv = *(const float4*)&Kp[(size_t)(jt*64 + lr) * DK + c];
            float4 vv = *(const float4*)&Vp[(size_t)(jt*64 + lr) * DK + c];
            Ks[lr][c+0]=kv.x; Ks[lr][c+1]=kv.y; Ks[lr][c+2]=kv.z; Ks[lr][c+3]=kv.w;
            Vs[lr][c+0]=vv.x; Vs[lr][c+1]=vv.y; Vs[lr][c+2]=vv.z; Vs[lr][c+3]=vv.w;
        }
        __syncthreads();

        // S = Q K^T / 8, 4x4 per thread
        float sa[4][4] = {};
#pragma unroll
        for (int kk = 0; kk < 64; kk++) {
            float a[4], b[4];
#pragma unroll
            for (int i = 0; i < 4; i++) a[i] = Qs[ty*4+i][kk];
#pragma unroll
            for (int j = 0; j < 4; j++) b[j] = Ks[tx*4+j][kk];
#pragma unroll
            for (int i = 0; i < 4; i++)
#pragma unroll
                for (int j = 0; j < 4; j++)
                    sa[i][j] += a[i] * b[j];
        }
#pragma unroll
        for (int i = 0; i < 4; i++)
#pragma unroll
            for (int j = 0; j < 4; j++)
                Ss[ty*4+i][tx*4+j] = sa[i][j] * 0.125f;
        __syncthreads();

        // online softmax update: 4 threads per row
        const int rr = tid >> 2;
        const int part = tid & 3;
        const int c0 = part * 16;
        float lm = -1e30f;
#pragma unroll
        for (int c = 0; c < 16; c++) lm = fmaxf(lm, Ss[rr][c0 + c]);
        red[rr][part] = lm;
        __syncthreads();
        const float mold = mS[rr];
        const float mnew = fmaxf(mold, fmaxf(fmaxf(red[rr][0], red[rr][1]),
                                             fmaxf(red[rr][2], red[rr][3])));
        __syncthreads();   // protect red[] reads before reuse
        float ls = 0.f;
#pragma unroll
        for (int c = 0; c < 16; c++) {
            float p = __expf(Ss[rr][c0 + c] - mnew);
            Ss[rr][c0 + c] = p;
            ls += p;
        }
        red[rr][part] = ls;
        if (part == 0) alphaS[rr] = __expf(mold - mnew);
        __syncthreads();
        if (part == 0) {
            lS[rr] = __expf(mold - mnew) * lS[rr]
                   + red[rr][0] + red[rr][1] + red[rr][2] + red[rr][3];
            mS[rr] = mnew;
        }

        // O = alpha*O + P V
        float al[4];
#pragma unroll
        for (int i = 0; i < 4; i++) al[i] = alphaS[ty*4+i];
#pragma unroll
        for (int i = 0; i < 4; i++)
#pragma unroll
            for (int j = 0; j < 4; j++) o[i][j] *= al[i];
#pragma unroll
        for (int t = 0; t < 64; t++) {
            float p[4], v[4];
#pragma unroll
            for (int i = 0; i < 4; i++) p[i] = Ss[ty*4+i][t];
#pragma unroll
            for (int j = 0; j < 4; j++) v[j] = Vs[t][tx*4+j];
#pragma unroll
            for (int i = 0; i < 4; i++)
#pragma unroll
                for (int j = 0; j < 4; j++)
                    o[i][j] += p[i] * v[j];
        }
        __syncthreads();
    }

    // epilogue: normalize by l, write ctx [b][s][h*64+k]
    const int b_ = bh >> 4, h_ = bh & 15;
    float linv[4];
#pragma unroll
    for (int i = 0; i < 4; i++) linv[i] = 1.f / lS[ty*4+i];
#pragma unroll
    for (int i = 0; i < 4; i++) {
        const int s_ = qt*64 + ty*4 + i;
        float4 v;
        v.x = o[i][0]*linv[i]; v.y = o[i][1]*linv[i];
        v.z = o[i][2]*linv[i]; v.w = o[i][3]*linv[i];
        *(float4*)&ctx[(size_t)(b_*SEQ + s_) * D_MODEL + h_*DK + tx*4] = v;
    }
}

// ---------------------------------------------------------------------------
// Kernel 3: output projection ctx @ Wo + bo, ReLU.
// grid = (M/64, D_MODEL/64)
// ---------------------------------------------------------------------------
__global__ __launch_bounds__(256) void oproj_kernel(
    const float* __restrict__ ctxp, const float* __restrict__ Wo,
    const float* __restrict__ bo, float* __restrict__ out)
{
    __shared__ float As[64][36];
    __shared__ float Bs[32][64];

    const int row0 = blockIdx.x * 64;
    const int e0   = blockIdx.y * 64;
    const int tid  = threadIdx.x;
    const int ty   = tid >> 4, tx = tid & 15;
    const int arow = tid >> 3;
    const int aseg = (tid & 7) * 4;
    const int wrow = tid >> 3;
    const int wcol = (tid & 7) * 8;

    float acc[4][4] = {};

    for (int k0 = 0; k0 < D_MODEL; k0 += 32) {
        float4 a0 = *(const float4*)&ctxp[(size_t)(row0 + arow)      * D_MODEL + k0 + aseg];
        float4 a1 = *(const float4*)&ctxp[(size_t)(row0 + arow + 32) * D_MODEL + k0 + aseg];
        float4 w0 = *(const float4*)&Wo[(size_t)(k0 + wrow) * D_MODEL + e0 + wcol];
        float4 w1 = *(const float4*)&Wo[(size_t)(k0 + wrow) * D_MODEL + e0 + wcol + 4];
        *(float4*)&As[arow][aseg]      = a0;
        *(float4*)&As[arow + 32][aseg] = a1;
        *(float4*)&Bs[wrow][wcol]      = w0;
        *(float4*)&Bs[wrow][wcol + 4]  = w1;
        __syncthreads();
#pragma unroll
        for (int kk = 0; kk < 32; kk++) {
            float a[4], b[4];
#pragma unroll
            for (int i = 0; i < 4; i++) a[i] = As[ty*4+i][kk];
#pragma unroll
            for (int j = 0; j < 4; j++) b[j] = Bs[kk][tx*4+j];
#pragma unroll
            for (int i = 0; i < 4; i++)
#pragma unroll
                for (int j = 0; j < 4; j++)
                    acc[i][j] += a[i] * b[j];
        }
        __syncthreads();
    }

    float bvals[4];
#pragma unroll
    for (int j = 0; j < 4; j++) bvals[j] = bo[e0 + tx*4 + j];
#pragma unroll
    for (int i = 0; i < 4; i++) {
        const int m = row0 + ty*4 + i;
        float4 v;
        v.x = fmaxf(acc[i][0] + bvals[0], 0.f);
        v.y = fmaxf(acc[i][1] + bvals[1], 0.f);
        v.z = fmaxf(acc[i][2] + bvals[2], 0.f);
        v.w = fmaxf(acc[i][3] + bvals[3], 0.f);
        *(float4*)&out[(size_t)m * D_MODEL + e0 + tx*4] = v;
    }
}

extern "C" void kernel_launch(void* const* d_in, const int* in_sizes, int n_in,
                              void* d_out, int out_size, void* d_ws, size_t ws_size,
                              hipStream_t stream) {
    const float* x  = (const float*)d_in[0];
    const float* Wq = (const float*)d_in[1];
    const float* bq = (const float*)d_in[2];
    const float* Wk = (const float*)d_in[3];
    const float* bk = (const float*)d_in[4];
    const float* Wv = (const float*)d_in[5];
    const float* bv = (const float*)d_in[6];
    const float* Wo = (const float*)d_in[7];
    const float* bo = (const float*)d_in[8];
    float* out = (float*)d_out;

    const size_t per = (size_t)NB * NH * SEQ * DK;  // 4,194,304 floats
    float* Qw = (float*)d_ws;
    float* Kw = Qw + per;
    float* Vw = Kw + per;
    float* Cw = Vw + per;

    qkv_kernel<<<dim3(64, 48), 256, 0, stream>>>(x, Wq, bq, Wk, bk, Wv, bv, Qw, Kw, Vw);
    attn_kernel<<<dim3(SEQ/64, NB*NH), 256, 0, stream>>>(Qw, Kw, Vw, Cw);
    oproj_kernel<<<dim3(64, D_MODEL/64), 256, 0, stream>>>(Cw, Wo, bo, out);
}

// Round 2
// 748.696 us; speedup vs baseline: 1.6259x; 1.6259x over previous
//
#include <hip/hip_runtime.h>
#include <cstddef>

#define D_MODEL 1024
#define DK 64
#define NH 16
#define NB 2
#define SEQ 2048

typedef __attribute__((ext_vector_type(8))) short bf16x8;
typedef __attribute__((ext_vector_type(4))) float floatx4;

static __device__ __forceinline__ unsigned short f2bf(float f) {
    union { float f; unsigned u; } v; v.f = f;
    unsigned r = (v.u + 0x7fffu + ((v.u >> 16) & 1u)) >> 16;
    return (unsigned short)r;
}

// ---------------------------------------------------------------------------
// Kernel 1: fused QKV projection + bias + ReLU (fp32 compute, bf16 output).
// Q,K written [b*h][s][dk] row-major bf16; V written TRANSPOSED [b*h][dk][s].
// grid = (M/64, 48): blockIdx.y -> (proj, head).
// ---------------------------------------------------------------------------
__global__ __launch_bounds__(256) void qkv_kernel(
    const float* __restrict__ x,
    const float* __restrict__ Wq, const float* __restrict__ bq,
    const float* __restrict__ Wk, const float* __restrict__ bk,
    const float* __restrict__ Wv, const float* __restrict__ bv,
    unsigned short* __restrict__ Qo, unsigned short* __restrict__ Ko,
    unsigned short* __restrict__ Vo)
{
    __shared__ float As[64][36];
    __shared__ float Bs[32][64];

    const int cb   = blockIdx.y;
    const int proj = cb >> 4;
    const int h    = cb & 15;
    const float* W; const float* bias; unsigned short* Out;
    if (proj == 0)      { W = Wq; bias = bq; Out = Qo; }
    else if (proj == 1) { W = Wk; bias = bk; Out = Ko; }
    else                { W = Wv; bias = bv; Out = Vo; }
    W    += (size_t)h * (D_MODEL * DK);
    bias += h * DK;

    const int row0 = blockIdx.x * 64;
    const int tid  = threadIdx.x;
    const int ty   = tid >> 4, tx = tid & 15;
    const int arow = tid >> 3;
    const int aseg = (tid & 7) * 4;
    const int wrow = tid >> 3;
    const int wcol = (tid & 7) * 8;

    float acc[4][4] = {};

    for (int k0 = 0; k0 < D_MODEL; k0 += 32) {
        float4 a0 = *(const float4*)&x[(size_t)(row0 + arow)      * D_MODEL + k0 + aseg];
        float4 a1 = *(const float4*)&x[(size_t)(row0 + arow + 32) * D_MODEL + k0 + aseg];
        float4 w0 = *(const float4*)&W[(size_t)(k0 + wrow) * DK + wcol];
        float4 w1 = *(const float4*)&W[(size_t)(k0 + wrow) * DK + wcol + 4];
        *(float4*)&As[arow][aseg]      = a0;
        *(float4*)&As[arow + 32][aseg] = a1;
        *(float4*)&Bs[wrow][wcol]      = w0;
        *(float4*)&Bs[wrow][wcol + 4]  = w1;
        __syncthreads();
#pragma unroll
        for (int kk = 0; kk < 32; kk++) {
            float a[4], b[4];
#pragma unroll
            for (int i = 0; i < 4; i++) a[i] = As[ty*4+i][kk];
#pragma unroll
            for (int j = 0; j < 4; j++) b[j] = Bs[kk][tx*4+j];
#pragma unroll
            for (int i = 0; i < 4; i++)
#pragma unroll
                for (int j = 0; j < 4; j++)
                    acc[i][j] += a[i] * b[j];
        }
        __syncthreads();
    }

    float bvals[4];
#pragma unroll
    for (int j = 0; j < 4; j++) bvals[j] = bias[tx*4+j];

    if (proj < 2) {
        // row-major bf16: Out[(bh*SEQ + s)*DK + dk], 8B packed stores
#pragma unroll
        for (int i = 0; i < 4; i++) {
            const int m  = row0 + ty*4 + i;
            const int b_ = m >> 11;
            const int s_ = m & (SEQ - 1);
            unsigned short o0 = f2bf(fmaxf(acc[i][0] + bvals[0], 0.f));
            unsigned short o1 = f2bf(fmaxf(acc[i][1] + bvals[1], 0.f));
            unsigned short o2 = f2bf(fmaxf(acc[i][2] + bvals[2], 0.f));
            unsigned short o3 = f2bf(fmaxf(acc[i][3] + bvals[3], 0.f));
            uint2 pk;
            pk.x = (unsigned)o0 | ((unsigned)o1 << 16);
            pk.y = (unsigned)o2 | ((unsigned)o3 << 16);
            *(uint2*)&Out[((size_t)(b_*NH + h) * SEQ + s_) * DK + tx*4] = pk;
        }
    } else {
        // transposed bf16: Out[(bh*DK + dk)*SEQ + s], scalar u16 stores
#pragma unroll
        for (int i = 0; i < 4; i++) {
            const int m  = row0 + ty*4 + i;
            const int b_ = m >> 11;
            const int s_ = m & (SEQ - 1);
#pragma unroll
            for (int j = 0; j < 4; j++) {
                Out[((size_t)(b_*NH + h) * DK + tx*4 + j) * SEQ + s_] =
                    f2bf(fmaxf(acc[i][j] + bvals[j], 0.f));
            }
        }
    }
}

// ---------------------------------------------------------------------------
// Kernel 2: flash attention, bf16 MFMA 16x16x32.
// Per wave: 16 queries vs all keys. S^T = K*Q^T so stats sit at lane&15.
// No K/V LDS staging (direct b128 global loads, L1/L2-served); P transposed
// C-layout -> A-layout through a per-wave LDS buffer. No barriers in loop.
// grid = 1024 linear blocks, XCD-swizzled: 4 heads per XCD -> KV fits L2.
// ---------------------------------------------------------------------------
__global__ __launch_bounds__(256) void attn_kernel(
    const unsigned short* __restrict__ Qb,
    const unsigned short* __restrict__ Kb,
    const unsigned short* __restrict__ Vt,
    float* __restrict__ ctx)
{
    __shared__ unsigned short Ps[4][16][72];   // stride 72: 16B-aligned rows, uniform bank quads

    const int blk = blockIdx.x;                // 0..1023
    const int xcd = blk & 7;
    const int j_  = blk >> 3;                  // 0..127
    const int bh  = xcd * 4 + (j_ & 3);        // 4 heads pinned per XCD
    const int qt  = j_ >> 2;                   // 0..31

    const int tid  = threadIdx.x;
    const int wv   = tid >> 6;
    const int lane = tid & 63;
    const int lq   = lane & 15;
    const int g    = lane >> 4;

    const int q0 = qt * 64 + wv * 16;
    const size_t qkBase = (size_t)bh * SEQ * DK;

    // Q B-fragments (held in regs for the whole loop): B[k=dk][n=q]
    bf16x8 qf0 = *(const bf16x8*)&Qb[qkBase + (size_t)(q0 + lq) * DK + g*8];
    bf16x8 qf1 = *(const bf16x8*)&Qb[qkBase + (size_t)(q0 + lq) * DK + 32 + g*8];

    const float C = 0.18033688011112042f;      // log2(e) / 8  (score scale folded)
    float m_run = -1e30f, l_run = 0.f;
    floatx4 acc[4];
#pragma unroll
    for (int i = 0; i < 4; i++) acc[i] = (floatx4){0.f, 0.f, 0.f, 0.f};

    for (int jt = 0; jt < SEQ/64; jt++) {
        const int kb = jt * 64;

        // ---- S^T = K * Q^T : D[m=key][n=query] ----
        floatx4 sacc[4];
#pragma unroll
        for (int mt = 0; mt < 4; mt++) sacc[mt] = (floatx4){0.f, 0.f, 0.f, 0.f};
#pragma unroll
        for (int mt = 0; mt < 4; mt++) {
            const unsigned short* kp = &Kb[qkBase + (size_t)(kb + mt*16 + lq) * DK + g*8];
            bf16x8 a0 = *(const bf16x8*)kp;
            bf16x8 a1 = *(const bf16x8*)(kp + 32);
            sacc[mt] = __builtin_amdgcn_mfma_f32_16x16x32_bf16(a0, qf0, sacc[mt], 0, 0, 0);
            sacc[mt] = __builtin_amdgcn_mfma_f32_16x16x32_bf16(a1, qf1, sacc[mt], 0, 0, 0);
        }

        // ---- online softmax for query q0+lq (replicated over g) ----
        float mx = sacc[0][0];
#pragma unroll
        for (int mt = 0; mt < 4; mt++)
#pragma unroll
            for (int r = 0; r < 4; r++) mx = fmaxf(mx, sacc[mt][r]);
        mx = fmaxf(mx, __shfl_xor(mx, 16, 64));
        mx = fmaxf(mx, __shfl_xor(mx, 32, 64));
        const float mnew  = fmaxf(m_run, mx);
        const float alpha = __builtin_amdgcn_exp2f((m_run - mnew) * C);

        float psum = 0.f;
        float pv[4][4];
#pragma unroll
        for (int mt = 0; mt < 4; mt++)
#pragma unroll
            for (int r = 0; r < 4; r++) {
                float p = __builtin_amdgcn_exp2f((sacc[mt][r] - mnew) * C);
                pv[mt][r] = p;
                psum += p;
            }
        psum += __shfl_xor(psum, 16, 64);
        psum += __shfl_xor(psum, 32, 64);
        l_run = l_run * alpha + psum;
        m_run = mnew;

        // ---- P: C-layout -> A-layout via per-wave LDS ----
#pragma unroll
        for (int mt = 0; mt < 4; mt++) {
            uint2 pk;
            pk.x = (unsigned)f2bf(pv[mt][0]) | ((unsigned)f2bf(pv[mt][1]) << 16);
            pk.y = (unsigned)f2bf(pv[mt][2]) | ((unsigned)f2bf(pv[mt][3]) << 16);
            *(uint2*)&Ps[wv][lq][mt*16 + g*4] = pk;   // key_local = 16mt+4g+r at col q
        }
        asm volatile("s_waitcnt lgkmcnt(0)" ::: "memory");  // same-wave write->read
        bf16x8 pa0 = *(const bf16x8*)&Ps[wv][lq][g*8];        // A[m=q][k=key 0..31]
        bf16x8 pa1 = *(const bf16x8*)&Ps[wv][lq][32 + g*8];   // keys 32..63

        // ---- rescale ctx rows (row q = 4g+r needs alpha from lane 4g+r) ----
        float ar[4];
#pragma unroll
        for (int r = 0; r < 4; r++) ar[r] = __shfl(alpha, g*4 + r, 64);
#pragma unroll
        for (int nt = 0; nt < 4; nt++)
#pragma unroll
            for (int r = 0; r < 4; r++) acc[nt][r] *= ar[r];

        // ---- ctx += P * V : B[k=key][n=dk] from transposed V ----
#pragma unroll
        for (int nt = 0; nt < 4; nt++) {
            const unsigned short* vp = &Vt[((size_t)bh * DK + nt*16 + lq) * SEQ + kb + g*8];
            bf16x8 v0 = *(const bf16x8*)vp;
            bf16x8 v1 = *(const bf16x8*)(vp + 32);
            acc[nt] = __builtin_amdgcn_mfma_f32_16x16x32_bf16(pa0, v0, acc[nt], 0, 0, 0);
            acc[nt] = __builtin_amdgcn_mfma_f32_16x16x32_bf16(pa1, v1, acc[nt], 0, 0, 0);
        }
    }

    // ---- epilogue: normalize, write ctx [b][s][h*64+dk] fp32 ----
    float lr[4];
#pragma unroll
    for (int r = 0; r < 4; r++) lr[r] = 1.f / __shfl(l_run, g*4 + r, 64);
    const int b_ = bh >> 4, h_ = bh & 15;
#pragma unroll
    for (int nt = 0; nt < 4; nt++)
#pragma unroll
        for (int r = 0; r < 4; r++) {
            const int q = q0 + g*4 + r;
            ctx[((size_t)(b_*SEQ) + q) * D_MODEL + h_*DK + nt*16 + lq] = acc[nt][r] * lr[r];
        }
}

// ---------------------------------------------------------------------------
// Kernel 3: output projection ctx @ Wo + bo, ReLU (fp32).
// ---------------------------------------------------------------------------
__global__ __launch_bounds__(256) void oproj_kernel(
    const float* __restrict__ ctxp, const float* __restrict__ Wo,
    const float* __restrict__ bo, float* __restrict__ out)
{
    __shared__ float As[64][36];
    __shared__ float Bs[32][64];

    const int row0 = blockIdx.x * 64;
    const int e0   = blockIdx.y * 64;
    const int tid  = threadIdx.x;
    const int ty   = tid >> 4, tx = tid & 15;
    const int arow = tid >> 3;
    const int aseg = (tid & 7) * 4;
    const int wrow = tid >> 3;
    const int wcol = (tid & 7) * 8;

    float acc[4][4] = {};

    for (int k0 = 0; k0 < D_MODEL; k0 += 32) {
        float4 a0 = *(const float4*)&ctxp[(size_t)(row0 + arow)      * D_MODEL + k0 + aseg];
        float4 a1 = *(const float4*)&ctxp[(size_t)(row0 + arow + 32) * D_MODEL + k0 + aseg];
        float4 w0 = *(const float4*)&Wo[(size_t)(k0 + wrow) * D_MODEL + e0 + wcol];
        float4 w1 = *(const float4*)&Wo[(size_t)(k0 + wrow) * D_MODEL + e0 + wcol + 4];
        *(float4*)&As[arow][aseg]      = a0;
        *(float4*)&As[arow + 32][aseg] = a1;
        *(float4*)&Bs[wrow][wcol]      = w0;
        *(float4*)&Bs[wrow][wcol + 4]  = w1;
        __syncthreads();
#pragma unroll
        for (int kk = 0; kk < 32; kk++) {
            float a[4], b[4];
#pragma unroll
            for (int i = 0; i < 4; i++) a[i] = As[ty*4+i][kk];
#pragma unroll
            for (int j = 0; j < 4; j++) b[j] = Bs[kk][tx*4+j];
#pragma unroll
            for (int i = 0; i < 4; i++)
#pragma unroll
                for (int j = 0; j < 4; j++)
                    acc[i][j] += a[i] * b[j];
        }
        __syncthreads();
    }

    float bvals[4];
#pragma unroll
    for (int j = 0; j < 4; j++) bvals[j] = bo[e0 + tx*4 + j];
#pragma unroll
    for (int i = 0; i < 4; i++) {
        const int m = row0 + ty*4 + i;
        float4 v;
        v.x = fmaxf(acc[i][0] + bvals[0], 0.f);
        v.y = fmaxf(acc[i][1] + bvals[1], 0.f);
        v.z = fmaxf(acc[i][2] + bvals[2], 0.f);
        v.w = fmaxf(acc[i][3] + bvals[3], 0.f);
        *(float4*)&out[(size_t)m * D_MODEL + e0 + tx*4] = v;
    }
}

extern "C" void kernel_launch(void* const* d_in, const int* in_sizes, int n_in,
                              void* d_out, int out_size, void* d_ws, size_t ws_size,
                              hipStream_t stream) {
    const float* x  = (const float*)d_in[0];
    const float* Wq = (const float*)d_in[1];
    const float* bq = (const float*)d_in[2];
    const float* Wk = (const float*)d_in[3];
    const float* bk = (const float*)d_in[4];
    const float* Wv = (const float*)d_in[5];
    const float* bv = (const float*)d_in[6];
    const float* Wo = (const float*)d_in[7];
    const float* bo = (const float*)d_in[8];
    float* out = (float*)d_out;

    const size_t perE = (size_t)NB * NH * SEQ * DK;   // 4,194,304 elements
    unsigned short* Qb = (unsigned short*)d_ws;       // 8 MB
    unsigned short* Kb = Qb + perE;                   // 8 MB
    unsigned short* Vt = Kb + perE;                   // 8 MB (transposed)
    float*          Cw = (float*)(Vt + perE);         // 16 MB fp32

    qkv_kernel<<<dim3(64, 48), 256, 0, stream>>>(x, Wq, bq, Wk, bk, Wv, bv, Qb, Kb, Vt);
    attn_kernel<<<dim3(1024), 256, 0, stream>>>(Qb, Kb, Vt, Cw);
    oproj_kernel<<<dim3(64, D_MODEL/64), 256, 0, stream>>>(Cw, Wo, bo, out);
}

// Round 3
// 371.974 us; speedup vs baseline: 3.2725x; 2.0128x over previous
//
#include <hip/hip_runtime.h>
#include <cstddef>

#define D_MODEL 1024
#define DK 64
#define NH 16
#define NB 2
#define SEQ 2048

typedef __attribute__((ext_vector_type(8))) short bf16x8;
typedef __attribute__((ext_vector_type(4))) float floatx4;

static __device__ __forceinline__ unsigned short f2bf(float f) {
    union { float f; unsigned u; } v; v.f = f;
    unsigned r = (v.u + 0x7fffu + ((v.u >> 16) & 1u)) >> 16;
    return (unsigned short)r;
}

static __device__ __forceinline__ void gld16(const unsigned short* g, unsigned short* l) {
    __builtin_amdgcn_global_load_lds(
        (const __attribute__((address_space(1))) unsigned int*)g,
        (__attribute__((address_space(3))) unsigned int*)l, 16, 0, 0);
}

// ---------------------------------------------------------------------------
// convert x fp32 -> bf16 (same layout [4096][1024])
// ---------------------------------------------------------------------------
__global__ __launch_bounds__(256) void convert_x(const float* __restrict__ x,
                                                 unsigned short* __restrict__ xb)
{
    const size_t i = ((size_t)blockIdx.x * 256 + threadIdx.x) * 16;
#pragma unroll
    for (int c = 0; c < 16; c += 4) {
        float4 v = *(const float4*)&x[i + c];
        uint2 pk;
        pk.x = (unsigned)f2bf(v.x) | ((unsigned)f2bf(v.y) << 16);
        pk.y = (unsigned)f2bf(v.z) | ((unsigned)f2bf(v.w) << 16);
        *(uint2*)&xb[i + c] = pk;
    }
}

// ---------------------------------------------------------------------------
// pack weights to n-major bf16 (B^T layout) via LDS 64x64 tile transpose.
// blocks 0..767: Wq/Wk/Wv [16][1024][64] -> Bqkv[3072][1024]
// blocks 768..1023: Wo [1024][1024] -> Bo[1024][1024]
// ---------------------------------------------------------------------------
__global__ __launch_bounds__(256) void pack_w(
    const float* __restrict__ Wq, const float* __restrict__ Wk,
    const float* __restrict__ Wv, const float* __restrict__ Wo,
    unsigned short* __restrict__ Bqkv, unsigned short* __restrict__ Bo)
{
    __shared__ float T[64][65];
    const int t   = blockIdx.x;
    const int tid = threadIdx.x;
    const int rr   = tid >> 2;          // 0..63
    const int cseg = (tid & 3) * 16;    // 0,16,32,48

    const float* src;
    unsigned short* dst;
    if (t < 768) {
        const int proj = t / 256, rem = t % 256;
        const int h = rem >> 4, d0 = (rem & 15) * 64;
        const float* W = proj == 0 ? Wq : (proj == 1 ? Wk : Wv);
        // read W[h][d0+rr][0..63]  (row stride 64)
        src = W + ((size_t)h * 1024 + d0) * 64;
#pragma unroll
        for (int c = 0; c < 16; c += 4) {
            float4 v = *(const float4*)&src[(size_t)rr * 64 + cseg + c];
            T[rr][cseg + c + 0] = v.x; T[rr][cseg + c + 1] = v.y;
            T[rr][cseg + c + 2] = v.z; T[rr][cseg + c + 3] = v.w;
        }
        __syncthreads();
        // write Bqkv[(proj*1024 + h*64 + rr)][d0 + cseg .. +16] = T[cseg+ii][rr]
        dst = &Bqkv[((size_t)proj * 1024 + h * 64 + rr) * 1024 + d0 + cseg];
    } else {
        const int t2 = t - 768;
        const int k0 = (t2 >> 4) * 64, nb0 = (t2 & 15) * 64;
        // read Wo[(k0+rr)][nb0 .. +64]
#pragma unroll
        for (int c = 0; c < 16; c += 4) {
            float4 v = *(const float4*)&Wo[(size_t)(k0 + rr) * 1024 + nb0 + cseg + c];
            T[rr][cseg + c + 0] = v.x; T[rr][cseg + c + 1] = v.y;
            T[rr][cseg + c + 2] = v.z; T[rr][cseg + c + 3] = v.w;
        }
        __syncthreads();
        // write Bo[(nb0+rr)][k0 + cseg .. +16] = T[cseg+ii][rr]
        dst = &Bo[(size_t)(nb0 + rr) * 1024 + k0 + cseg];
    }
    unsigned int w[8];
#pragma unroll
    for (int ii = 0; ii < 8; ii++) {
        unsigned short lo = f2bf(T[cseg + ii * 2 + 0][rr]);
        unsigned short hi = f2bf(T[cseg + ii * 2 + 1][rr]);
        w[ii] = (unsigned)lo | ((unsigned)hi << 16);
    }
    *(uint4*)(dst + 0) = make_uint4(w[0], w[1], w[2], w[3]);
    *(uint4*)(dst + 8) = make_uint4(w[4], w[5], w[6], w[7]);
}

// ---------------------------------------------------------------------------
// gemm_qkv: C[4096][3072] = xbf[4096][1024] @ Bqkv^T  (Bqkv is n-major)
// m97 structure: 128x128 tile, BK=32, global_load_lds w16, 4 waves x 4x4 MFMA.
// Epilogue: +bias, ReLU, bf16, scatter to Q/K row-major [bh][s][dk] and
// V transposed [bh][dk][s].
// ---------------------------------------------------------------------------
__global__ __launch_bounds__(256) void gemm_qkv(
    const unsigned short* __restrict__ Abf,
    const unsigned short* __restrict__ Bp,
    const float* __restrict__ bq, const float* __restrict__ bk,
    const float* __restrict__ bv,
    unsigned short* __restrict__ Qo, unsigned short* __restrict__ Ko,
    unsigned short* __restrict__ Vo)
{
    __shared__ __align__(16) unsigned short As[128 * 32];
    __shared__ __align__(16) unsigned short Bs[128 * 32];

    const int tid  = threadIdx.x;
    const int wv   = tid >> 6, lane = tid & 63;
    const int m0   = blockIdx.x * 128;
    const int n0   = blockIdx.y * 128;
    const int lq   = lane & 15, g = lane >> 4;
    const int wm   = (wv >> 1) * 64;
    const int wn   = (wv & 1) * 64;
    const int srow = lane >> 2;          // 0..15 within chunk
    const int sseg = (lane & 3) * 8;     // k element offset

    floatx4 acc[4][4];
#pragma unroll
    for (int i = 0; i < 4; i++)
#pragma unroll
        for (int j = 0; j < 4; j++) acc[i][j] = (floatx4){0.f, 0.f, 0.f, 0.f};

    for (int k0 = 0; k0 < 1024; k0 += 32) {
#pragma unroll
        for (int r = 0; r < 2; r++) {
            const int chunk = wv * 2 + r;
            const int row   = chunk * 16 + srow;
            gld16(&Abf[(size_t)(m0 + row) * 1024 + k0 + sseg], &As[chunk * 512]);
            gld16(&Bp [(size_t)(n0 + row) * 1024 + k0 + sseg], &Bs[chunk * 512]);
        }
        __syncthreads();
        bf16x8 af[4], bfv[4];
#pragma unroll
        for (int i = 0; i < 4; i++)
            af[i] = *(const bf16x8*)&As[(wm + i * 16 + lq) * 32 + g * 8];
#pragma unroll
        for (int j = 0; j < 4; j++)
            bfv[j] = *(const bf16x8*)&Bs[(wn + j * 16 + lq) * 32 + g * 8];
#pragma unroll
        for (int i = 0; i < 4; i++)
#pragma unroll
            for (int j = 0; j < 4; j++)
                acc[i][j] = __builtin_amdgcn_mfma_f32_16x16x32_bf16(af[i], bfv[j], acc[i][j], 0, 0, 0);
        __syncthreads();
    }

    const int proj = n0 >> 10;
    const float* bias = proj == 0 ? bq : (proj == 1 ? bk : bv);
    unsigned short* OutQK = proj == 0 ? Qo : Ko;

#pragma unroll
    for (int j = 0; j < 4; j++) {
        const int n  = n0 + wn + j * 16 + lq;
        const int nn = n & 1023;
        const int h  = nn >> 6, dk = nn & 63;
        const float bb = bias[nn];
#pragma unroll
        for (int i = 0; i < 4; i++) {
            const int mbase = m0 + wm + i * 16 + g * 4;
            if (proj < 2) {
#pragma unroll
                for (int r = 0; r < 4; r++) {
                    const int m  = mbase + r;
                    const int b_ = m >> 11, s_ = m & (SEQ - 1);
                    OutQK[((size_t)(b_ * NH + h) * SEQ + s_) * DK + dk] =
                        f2bf(fmaxf(acc[i][j][r] + bb, 0.f));
                }
            } else {
                const int b_ = mbase >> 11, s_ = mbase & (SEQ - 1);  // 4-aligned
                uint2 pk;
                pk.x = (unsigned)f2bf(fmaxf(acc[i][j][0] + bb, 0.f))
                     | ((unsigned)f2bf(fmaxf(acc[i][j][1] + bb, 0.f)) << 16);
                pk.y = (unsigned)f2bf(fmaxf(acc[i][j][2] + bb, 0.f))
                     | ((unsigned)f2bf(fmaxf(acc[i][j][3] + bb, 0.f)) << 16);
                *(uint2*)&Vo[((size_t)(b_ * NH + h) * DK + dk) * SEQ + s_] = pk;
            }
        }
    }
}

// ---------------------------------------------------------------------------
// flash attention, bf16 MFMA (unchanged from R2 except bf16 ctx output).
// ---------------------------------------------------------------------------
__global__ __launch_bounds__(256) void attn_kernel(
    const unsigned short* __restrict__ Qb,
    const unsigned short* __restrict__ Kb,
    const unsigned short* __restrict__ Vt,
    unsigned short* __restrict__ ctxb)
{
    __shared__ __align__(16) unsigned short Ps[4][16][72];

    const int blk = blockIdx.x;
    const int xcd = blk & 7;
    const int j_  = blk >> 3;
    const int bh  = xcd * 4 + (j_ & 3);
    const int qt  = j_ >> 2;

    const int tid  = threadIdx.x;
    const int wv   = tid >> 6;
    const int lane = tid & 63;
    const int lq   = lane & 15;
    const int g    = lane >> 4;

    const int q0 = qt * 64 + wv * 16;
    const size_t qkBase = (size_t)bh * SEQ * DK;

    bf16x8 qf0 = *(const bf16x8*)&Qb[qkBase + (size_t)(q0 + lq) * DK + g * 8];
    bf16x8 qf1 = *(const bf16x8*)&Qb[qkBase + (size_t)(q0 + lq) * DK + 32 + g * 8];

    const float C = 0.18033688011112042f;   // log2(e)/8
    float m_run = -1e30f, l_run = 0.f;
    floatx4 acc[4];
#pragma unroll
    for (int i = 0; i < 4; i++) acc[i] = (floatx4){0.f, 0.f, 0.f, 0.f};

    for (int jt = 0; jt < SEQ / 64; jt++) {
        const int kb = jt * 64;

        floatx4 sacc[4];
#pragma unroll
        for (int mt = 0; mt < 4; mt++) sacc[mt] = (floatx4){0.f, 0.f, 0.f, 0.f};
#pragma unroll
        for (int mt = 0; mt < 4; mt++) {
            const unsigned short* kp = &Kb[qkBase + (size_t)(kb + mt * 16 + lq) * DK + g * 8];
            bf16x8 a0 = *(const bf16x8*)kp;
            bf16x8 a1 = *(const bf16x8*)(kp + 32);
            sacc[mt] = __builtin_amdgcn_mfma_f32_16x16x32_bf16(a0, qf0, sacc[mt], 0, 0, 0);
            sacc[mt] = __builtin_amdgcn_mfma_f32_16x16x32_bf16(a1, qf1, sacc[mt], 0, 0, 0);
        }

        float mx = sacc[0][0];
#pragma unroll
        for (int mt = 0; mt < 4; mt++)
#pragma unroll
            for (int r = 0; r < 4; r++) mx = fmaxf(mx, sacc[mt][r]);
        mx = fmaxf(mx, __shfl_xor(mx, 16, 64));
        mx = fmaxf(mx, __shfl_xor(mx, 32, 64));
        const float mnew  = fmaxf(m_run, mx);
        const float alpha = __builtin_amdgcn_exp2f((m_run - mnew) * C);

        float psum = 0.f;
        float pv[4][4];
#pragma unroll
        for (int mt = 0; mt < 4; mt++)
#pragma unroll
            for (int r = 0; r < 4; r++) {
                float p = __builtin_amdgcn_exp2f((sacc[mt][r] - mnew) * C);
                pv[mt][r] = p;
                psum += p;
            }
        psum += __shfl_xor(psum, 16, 64);
        psum += __shfl_xor(psum, 32, 64);
        l_run = l_run * alpha + psum;
        m_run = mnew;

#pragma unroll
        for (int mt = 0; mt < 4; mt++) {
            uint2 pk;
            pk.x = (unsigned)f2bf(pv[mt][0]) | ((unsigned)f2bf(pv[mt][1]) << 16);
            pk.y = (unsigned)f2bf(pv[mt][2]) | ((unsigned)f2bf(pv[mt][3]) << 16);
            *(uint2*)&Ps[wv][lq][mt * 16 + g * 4] = pk;
        }
        asm volatile("s_waitcnt lgkmcnt(0)" ::: "memory");
        bf16x8 pa0 = *(const bf16x8*)&Ps[wv][lq][g * 8];
        bf16x8 pa1 = *(const bf16x8*)&Ps[wv][lq][32 + g * 8];

        float ar[4];
#pragma unroll
        for (int r = 0; r < 4; r++) ar[r] = __shfl(alpha, g * 4 + r, 64);
#pragma unroll
        for (int nt = 0; nt < 4; nt++)
#pragma unroll
            for (int r = 0; r < 4; r++) acc[nt][r] *= ar[r];

#pragma unroll
        for (int nt = 0; nt < 4; nt++) {
            const unsigned short* vp = &Vt[((size_t)bh * DK + nt * 16 + lq) * SEQ + kb + g * 8];
            bf16x8 v0 = *(const bf16x8*)vp;
            bf16x8 v1 = *(const bf16x8*)(vp + 32);
            acc[nt] = __builtin_amdgcn_mfma_f32_16x16x32_bf16(pa0, v0, acc[nt], 0, 0, 0);
            acc[nt] = __builtin_amdgcn_mfma_f32_16x16x32_bf16(pa1, v1, acc[nt], 0, 0, 0);
        }
    }

    float lr[4];
#pragma unroll
    for (int r = 0; r < 4; r++) lr[r] = 1.f / __shfl(l_run, g * 4 + r, 64);
    const int b_ = bh >> 4, h_ = bh & 15;
#pragma unroll
    for (int nt = 0; nt < 4; nt++)
#pragma unroll
        for (int r = 0; r < 4; r++) {
            const int q = q0 + g * 4 + r;
            ctxb[((size_t)(b_ * SEQ) + q) * D_MODEL + h_ * DK + nt * 16 + lq] =
                f2bf(acc[nt][r] * lr[r]);
        }
}

// ---------------------------------------------------------------------------
// gemm_o: out[4096][1024] = relu(ctxbf @ Wo + bo), fp32 out. Same structure.
// ---------------------------------------------------------------------------
__global__ __launch_bounds__(256) void gemm_o(
    const unsigned short* __restrict__ Abf,
    const unsigned short* __restrict__ Bp,     // [1024][1024] n-major
    const float* __restrict__ bo,
    float* __restrict__ out)
{
    __shared__ __align__(16) unsigned short As[128 * 32];
    __shared__ __align__(16) unsigned short Bs[128 * 32];

    const int tid  = threadIdx.x;
    const int wv   = tid >> 6, lane = tid & 63;
    const int m0   = blockIdx.x * 128;
    const int n0   = blockIdx.y * 128;
    const int lq   = lane & 15, g = lane >> 4;
    const int wm   = (wv >> 1) * 64;
    const int wn   = (wv & 1) * 64;
    const int srow = lane >> 2;
    const int sseg = (lane & 3) * 8;

    floatx4 acc[4][4];
#pragma unroll
    for (int i = 0; i < 4; i++)
#pragma unroll
        for (int j = 0; j < 4; j++) acc[i][j] = (floatx4){0.f, 0.f, 0.f, 0.f};

    for (int k0 = 0; k0 < 1024; k0 += 32) {
#pragma unroll
        for (int r = 0; r < 2; r++) {
            const int chunk = wv * 2 + r;
            const int row   = chunk * 16 + srow;
            gld16(&Abf[(size_t)(m0 + row) * 1024 + k0 + sseg], &As[chunk * 512]);
            gld16(&Bp [(size_t)(n0 + row) * 1024 + k0 + sseg], &Bs[chunk * 512]);
        }
        __syncthreads();
        bf16x8 af[4], bfv[4];
#pragma unroll
        for (int i = 0; i < 4; i++)
            af[i] = *(const bf16x8*)&As[(wm + i * 16 + lq) * 32 + g * 8];
#pragma unroll
        for (int j = 0; j < 4; j++)
            bfv[j] = *(const bf16x8*)&Bs[(wn + j * 16 + lq) * 32 + g * 8];
#pragma unroll
        for (int i = 0; i < 4; i++)
#pragma unroll
            for (int j = 0; j < 4; j++)
                acc[i][j] = __builtin_amdgcn_mfma_f32_16x16x32_bf16(af[i], bfv[j], acc[i][j], 0, 0, 0);
        __syncthreads();
    }

#pragma unroll
    for (int j = 0; j < 4; j++) {
        const int n  = n0 + wn + j * 16 + lq;
        const float bb = bo[n];
#pragma unroll
        for (int i = 0; i < 4; i++) {
#pragma unroll
            for (int r = 0; r < 4; r++) {
                const int m = m0 + wm + i * 16 + g * 4 + r;
                out[(size_t)m * 1024 + n] = fmaxf(acc[i][j][r] + bb, 0.f);
            }
        }
    }
}

extern "C" void kernel_launch(void* const* d_in, const int* in_sizes, int n_in,
                              void* d_out, int out_size, void* d_ws, size_t ws_size,
                              hipStream_t stream) {
    const float* x  = (const float*)d_in[0];
    const float* Wq = (const float*)d_in[1];
    const float* bq = (const float*)d_in[2];
    const float* Wk = (const float*)d_in[3];
    const float* bk = (const float*)d_in[4];
    const float* Wv = (const float*)d_in[5];
    const float* bv = (const float*)d_in[6];
    const float* Wo = (const float*)d_in[7];
    const float* bo = (const float*)d_in[8];
    float* out = (float*)d_out;

    const size_t perE = (size_t)NB * NH * SEQ * DK;      // 4,194,304
    unsigned short* xbf  = (unsigned short*)d_ws;        // 8 MB
    unsigned short* Bqkv = xbf  + (size_t)4096 * 1024;   // 6 MB
    unsigned short* Bo   = Bqkv + (size_t)3072 * 1024;   // 2 MB
    unsigned short* Qb   = Bo   + (size_t)1024 * 1024;   // 8 MB
    unsigned short* Kb   = Qb + perE;                    // 8 MB
    unsigned short* Vt   = Kb + perE;                    // 8 MB
    unsigned short* Cbf  = Vt + perE;                    // 8 MB

    convert_x<<<1024, 256, 0, stream>>>(x, xbf);
    pack_w<<<1024, 256, 0, stream>>>(Wq, Wk, Wv, Wo, Bqkv, Bo);
    gemm_qkv<<<dim3(32, 24), 256, 0, stream>>>(xbf, Bqkv, bq, bk, bv, Qb, Kb, Vt);
    attn_kernel<<<1024, 256, 0, stream>>>(Qb, Kb, Vt, Cbf);
    gemm_o<<<dim3(32, 8), 256, 0, stream>>>(Cbf, Bo, bo, out);
}